// Round 2
// baseline (564.558 us; speedup 1.0000x reference)
//
#include <hip/hip_runtime.h>
#include <hip/hip_bf16.h>
#include <cstdint>

typedef unsigned short u16;
typedef __attribute__((ext_vector_type(8))) short short8;   // 8 bf16 = 4 VGPRs (MFMA A/B frag)
typedef __attribute__((ext_vector_type(4))) float f32x4;    // MFMA C/D frag

// round-to-nearest-even fp32 -> bf16 bits
__device__ __forceinline__ u16 f2bf(float f) {
  unsigned u = __float_as_uint(f);
  u += 0x7fffu + ((u >> 16) & 1u);
  return (u16)(u >> 16);
}

// ---- kernel 1: x = inputs / ||inputs||  (fp32 -> bf16), one block per row ----
__global__ void norm_cast_kernel(const float* __restrict__ in, u16* __restrict__ xb) {
  const int row = blockIdx.x;
  const int t = threadIdx.x;           // 256 threads, D = 256
  float v = in[row * 256 + t];
  float s = v * v;
  #pragma unroll
  for (int off = 32; off >= 1; off >>= 1) s += __shfl_xor(s, off, 64);
  __shared__ float wsum[4];
  if ((t & 63) == 0) wsum[t >> 6] = s;
  __syncthreads();
  const float tot = wsum[0] + wsum[1] + wsum[2] + wsum[3];
  xb[row * 256 + t] = f2bf(v * rsqrtf(tot));
}

// ---- kernel 2: features fp32 -> bf16 bank in workspace ----
__global__ void cvt_bf16_kernel(const float4* __restrict__ in, ushort4* __restrict__ out, int n4) {
  const int i = blockIdx.x * 256 + threadIdx.x;
  if (i < n4) {
    float4 v = in[i];
    out[i] = make_ushort4(f2bf(v.x), f2bf(v.y), f2bf(v.z), f2bf(v.w));
  }
}

// ---- kernel 3: C[M,N] = (X . F^T) * 20, bf16 MFMA ----
// BM=BN=128, BK=64 (4 K-iters), 256 threads = 4 waves in 2x2 (each wave 64x64).
// Epilogue goes through LDS so global stores are row-contiguous dwordx4.
__global__ __launch_bounds__(256) void gemm_kernel(
    const u16* __restrict__ A,      // x bf16 [1024][256]
    const u16* __restrict__ Bbf,    // features bf16 [N][256]
    float* __restrict__ C, int Nn)
{
  // staging: As 128x64 bf16 (16 KB) + Bs 128x64 bf16 (16 KB) = 32 KB
  // epilogue: 64 rows x 132 floats = 33792 B (reuses the same buffer)
  __shared__ char smem[64 * 132 * 4];
  u16* As = (u16*)smem;
  u16* Bs = (u16*)(smem + 128 * 64 * 2);

  const int tid  = threadIdx.x;
  const int wave = tid >> 6;
  const int lane = tid & 63;
  const int m0 = blockIdx.x * 128;       // grid.x = 8 (fast) -> feature-tile L2/L3 reuse
  const int n0 = blockIdx.y * 128;
  const int wm = (wave & 1) * 64;
  const int wn = (wave >> 1) * 64;

  f32x4 acc[4][4] = {};

  // staging mapping: round r, thread tid loads 16 B; LDS dest = base + lane*16 (contiguous)
  // row = r*32 + wave*8 + (lane>>3), k-chunk = (lane&7)*8 elements
  const int srow   = wave * 8 + (lane >> 3);
  const int schunk = (lane & 7) * 8;

  for (int k0 = 0; k0 < 256; k0 += 64) {
    #pragma unroll
    for (int r = 0; r < 4; ++r) {
      // ---- A tile ----
      {
        const u16* gp = A + (size_t)(m0 + r * 32 + srow) * 256 + k0 + schunk;
        u16* lp = As + (r * 4 + wave) * 512;   // (r*256 + wave*64) lane-loads * 8 elems
        __builtin_amdgcn_global_load_lds(
            (const __attribute__((address_space(1))) void*)gp,
            (__attribute__((address_space(3))) void*)lp, 16, 0, 0);
      }
      // ---- B tile ----
      {
        int grow = n0 + r * 32 + srow;
        if (grow >= Nn) grow = Nn - 1;         // clamp tail; unused at store
        const u16* gp = Bbf + (size_t)grow * 256 + k0 + schunk;
        u16* lp = Bs + (r * 4 + wave) * 512;
        __builtin_amdgcn_global_load_lds(
            (const __attribute__((address_space(1))) void*)gp,
            (__attribute__((address_space(3))) void*)lp, 16, 0, 0);
      }
    }
    __syncthreads();

    const int fr = lane & 15;            // frag row (m for A, n for B)
    const int kc = (lane >> 4) * 8;      // frag k chunk within a 32-wide K slice
    #pragma unroll
    for (int kk = 0; kk < 2; ++kk) {
      short8 af[4], bfr[4];
      #pragma unroll
      for (int i = 0; i < 4; ++i) {
        af[i]  = *(const short8*)(&As[(wm + i * 16 + fr) * 64 + kk * 32 + kc]);
        bfr[i] = *(const short8*)(&Bs[(wn + i * 16 + fr) * 64 + kk * 32 + kc]);
      }
      #pragma unroll
      for (int mi = 0; mi < 4; ++mi)
        #pragma unroll
        for (int ni = 0; ni < 4; ++ni)
          acc[mi][ni] = __builtin_amdgcn_mfma_f32_16x16x32_bf16(af[mi], bfr[ni], acc[mi][ni], 0, 0, 0);
    }
    __syncthreads();
  }

  // ---- epilogue: LDS-assembled coalesced stores ----
  // C/D layout: col=lane&15, row=(lane>>4)*4+reg
  const int col   = lane & 15;
  const int rquad = (lane >> 4) * 4;
  float* ep = (float*)smem;              // [64][132] fp32, +4 pad kills write conflicts
  const int c4    = (tid & 31) * 4;      // store col within the 128-wide tile
  const int rbase = tid >> 5;            // 0..7

  #pragma unroll
  for (int h = 0; h < 2; ++h) {
    if (h) __syncthreads();              // protect ep reuse between halves
    if (wm == h * 64) {
      #pragma unroll
      for (int mi = 0; mi < 4; ++mi)
        #pragma unroll
        for (int ni = 0; ni < 4; ++ni)
          #pragma unroll
          for (int i = 0; i < 4; ++i)
            ep[(mi * 16 + rquad + i) * 132 + wn + ni * 16 + col] = acc[mi][ni][i] * 20.0f;
    }
    __syncthreads();
    #pragma unroll
    for (int rr = 0; rr < 8; ++rr) {
      const int row = rr * 8 + rbase;
      const int gn  = n0 + c4;
      float4 v = *(const float4*)&ep[row * 132 + c4];
      float* cp = C + (size_t)(m0 + h * 64 + row) * Nn + gn;
      if (gn + 4 <= Nn) {
        *(float4*)cp = v;
      } else {
        for (int j = 0; gn + j < Nn; ++j) cp[j] = ((const float*)&v)[j];
      }
    }
  }
}

extern "C" void kernel_launch(void* const* d_in, const int* in_sizes, int n_in,
                              void* d_out, int out_size, void* d_ws, size_t ws_size,
                              hipStream_t stream) {
  const float* inputs   = (const float*)d_in[0];
  // d_in[1] (targets) is dead for the forward output
  const float* features = (const float*)d_in[2];
  float* out = (float*)d_out;

  const int Bv = in_sizes[1];            // 1024
  const int Dv = in_sizes[0] / Bv;       // 256
  const int Nn = in_sizes[2] / Dv;       // 100000

  u16* xb = (u16*)d_ws;                                         // bf16 x: B*D
  const size_t x_bytes = ((size_t)Bv * Dv * 2 + 255) & ~(size_t)255;
  u16* fb = (u16*)((char*)d_ws + x_bytes);                      // bf16 features: N*D

  norm_cast_kernel<<<dim3(Bv), dim3(256), 0, stream>>>(inputs, xb);

  const int n4 = (Nn * Dv) / 4;
  cvt_bf16_kernel<<<dim3((n4 + 255) / 256), dim3(256), 0, stream>>>(
      (const float4*)features, (ushort4*)fb, n4);

  dim3 grid(Bv / 128, (Nn + 127) / 128);
  gemm_kernel<<<grid, dim3(256), 0, stream>>>(xb, fb, out, Nn);
}